// Round 19
// baseline (887.824 us; speedup 1.0000x reference)
//
#include <hip/hip_runtime.h>
#include <cmath>

#define NB 512
#define SEQ 301
// 0.25 * log2(e): folded so attention can use exp2 (native v_exp_f32)
#define QSCALE 0.36067376022f

using f32x4  = __attribute__((ext_vector_type(4))) float;
using s16x4  = __attribute__((ext_vector_type(4))) short;
using s16x8  = __attribute__((ext_vector_type(8))) short;

#if __has_builtin(__builtin_amdgcn_exp2f)
#define EX2(x) __builtin_amdgcn_exp2f(x)
#else
#define EX2(x) exp2f(x)
#endif

__device__ __forceinline__ unsigned short f2bf(float f) {
  unsigned int u = __builtin_bit_cast(unsigned int, f);
  u += 0x7fffu + ((u >> 16) & 1u);
  return (unsigned short)(u >> 16);
}

// pack 2 floats -> bf16x2 (round-half-up) in 3 VALU ops: 2 adds + v_perm
__device__ __forceinline__ unsigned int pkbf(float lo, float hi) {
  unsigned int ulo = __builtin_bit_cast(unsigned int, lo) + 0x8000u;
  unsigned int uhi = __builtin_bit_cast(unsigned int, hi) + 0x8000u;
  return __builtin_amdgcn_perm(uhi, ulo, 0x07060302u);
}

__device__ __forceinline__ s16x4 pk4f(float a, float b, float c, float d) {
  uint2 u = make_uint2(pkbf(a, b), pkbf(c, d));
  return __builtin_bit_cast(s16x4, u);
}

__device__ __forceinline__ s16x4 pk4(float4 v) {
  return pk4f(v.x, v.y, v.z, v.w);
}

__device__ __forceinline__ f32x4 mm16(s16x4 a, s16x4 b, f32x4 c) {
  return __builtin_amdgcn_mfma_f32_16x16x16bf16_1k(a, b, c, 0, 0, 0);
}

__device__ __forceinline__ f32x4 mm32(s16x8 a, s16x8 b, f32x4 c) {
  return __builtin_amdgcn_mfma_f32_16x16x32_bf16(a, b, c, 0, 0, 0);
}

__device__ __forceinline__ s16x8 cat8(s16x4 a, s16x4 b) {
  return __builtin_shufflevector(a, b, 0, 1, 2, 3, 4, 5, 6, 7);
}

// exact-enough gelu: erf via A&S 7.1.26 (|err|<1.5e-7), native exp2
__device__ __forceinline__ float gelu_f(float a) {
  float z = fabsf(a) * 0.70710678f;
  float t = 1.f / (1.f + 0.3275911f * z);
  float poly = t*(0.254829592f + t*(-0.284496736f + t*(1.421413741f +
               t*(-1.453152027f + t*1.061405429f))));
  float e = EX2(-z*z*1.44269504f);
  float erfa = 1.f - poly*e;
  float erfz = copysignf(erfa, a);
  return 0.5f*a*(1.f + erfz);
}

// ---------------- K0a: one-shot conv2 weight reorg -> [kw*32+o2][148] bf16 (pad zero)
__global__ __launch_bounds__(256) void k_prep(const float* __restrict__ w2c,
    unsigned short* __restrict__ wt2g) {
  int i = blockIdx.x*256 + threadIdx.x;
  if (i >= 96*148) return;
  int row = i/148, k = i - row*148;
  int kw_ = row >> 5, o2 = row & 31;
  unsigned short v = 0;
  if (k < 144) {
    int ci = k/9, r_ = k - ci*9;
    v = f2bf(w2c[o2*432 + ci*27 + r_*3 + kw_]);
  }
  wt2g[i] = v;
}

// ---------------- K0b: one-shot patch weight pad -> pwt[64][32] bf16 (k>=25 zero)
__global__ __launch_bounds__(256) void k_prep2(const float* __restrict__ pw,
    unsigned short* __restrict__ pwt) {
  int i = blockIdx.x*256 + threadIdx.x;
  if (i >= 64*32) return;
  int d = i >> 5, k = i & 31;
  pwt[i] = (k < 25) ? f2bf(pw[d*25 + k]) : (unsigned short)0;
}

// ---------------- K1: SSE gate
__global__ __launch_bounds__(64) void k_sse(const float* __restrict__ xin,
    const float* __restrict__ sw, const float* __restrict__ sb, float* __restrict__ xs) {
  int blk = blockIdx.x; int b = blk / 25, p = blk % 25; int lane = threadIdx.x;
  const float* src = xin + (size_t)b*7500 + p*300;
  float s = 0.f;
  for (int c = lane; c < 300; c += 64) s += src[c]*sw[c];
  #pragma unroll
  for (int o = 32; o > 0; o >>= 1) s += __shfl_down(s, o, 64);
  s = __shfl(s, 0, 64);
  float sq = 1.f/(1.f + __expf(-(s + sb[0])));
  float* dst = xs + (size_t)b*7500 + p*300;
  for (int c = lane; c < 300; c += 64) dst[c] = src[c]*sq;
}

// ---------------- K2: fused conv1+conv2 (MFMA, conv1 output in LDS only)
__global__ __launch_bounds__(256) void k_conv12(const float* __restrict__ xs,
    const float* __restrict__ w1c, const float* __restrict__ b1c,
    const unsigned short* __restrict__ wt2g, const float* __restrict__ b2c,
    float* __restrict__ c2) {
  int blk = blockIdx.x; int b = blk >> 2; int chunk = blk & 3;
  int w0 = chunk*73;
  int tid = threadIdx.x;
  int lane = tid & 63, wv = tid >> 6;
  int lm = lane & 15, lq = lane >> 4;
  __shared__ unsigned short xss[32*88];
  __shared__ unsigned short c1s[84*148];
  __shared__ alignas(8) unsigned short wt_s[96*148];

  const float* src = xs + (size_t)b*7500;
  for (int i = tid; i < 2025; i += 256) {
    int p = i/81, c = i - p*81;
    xss[p*88 + c] = f2bf(src[p*300 + w0 + c]);
  }
  for (int i = tid; i < 7*88; i += 256) xss[25*88 + i] = 0;
  for (int i = tid; i < 25*7; i += 256) { int p = i/7, c = 81 + i%7; xss[p*88 + c] = 0; }
  for (int i = tid; i < 9*148; i += 256) c1s[75*148 + i] = 0;
  {
    const uint2* wsrc = (const uint2*)wt2g;
    uint2* wdst = (uint2*)wt_s;
    for (int i = tid; i < 3552; i += 256) wdst[i] = wsrc[i];
  }

  s16x4 Af[4]; int P[4][4]; float bv[4];
  #pragma unroll
  for (int r = 0; r < 4; ++r) bv[r] = b1c[lq*4 + r];
  #pragma unroll
  for (int kc = 0; kc < 4; ++kc) {
    short e[4];
    #pragma unroll
    for (int j = 0; j < 4; ++j) {
      int k = kc*16 + lq*4 + j;
      float wf = (k < 63) ? w1c[lm*63 + k] : 0.f;
      e[j] = (short)f2bf(wf);
      int r_ = k/7, kw_ = k - r_*7;
      int kd = r_/3, kh = r_ - kd*3;
      P[kc][j] = (kd*5 + kh)*88 + kw_;
    }
    s16x4 a; a.x = e[0]; a.y = e[1]; a.z = e[2]; a.w = e[3];
    Af[kc] = a;
  }
  __syncthreads();

  for (int idx = wv; idx < 45; idx += 4) {
    int dh = idx/5, pt = idx - dh*5;
    int d0 = dh/3, h0 = dh - d0*3;
    int base = (d0*5 + h0)*88 + pt*16 + lm;
    f32x4 acc = {bv[0], bv[1], bv[2], bv[3]};
    #pragma unroll
    for (int kc = 0; kc < 4; ++kc) {
      s16x4 Bf;
      Bf.x = (short)xss[base + P[kc][0]];
      Bf.y = (short)xss[base + P[kc][1]];
      Bf.z = (short)xss[base + P[kc][2]];
      Bf.w = (short)xss[base + P[kc][3]];
      acc = mm16(Af[kc], Bf, acc);
    }
    int lw = pt*16 + lm;
    if (lw < 75) {
      unsigned short* dst = c1s + lw*148 + dh;
      #pragma unroll
      for (int r = 0; r < 4; ++r)
        dst[(lq*4 + r)*9] = f2bf(fmaxf(acc[r], 0.f));
    }
  }
  __syncthreads();

  float bvo0 = b2c[lm], bvo1 = b2c[16 + lm];
  for (int task = wv; task < 10; task += 4) {
    int pt = task >> 1, ot = task & 1;
    float bb = ot ? bvo1 : bvo0;
    f32x4 acc = {bb, bb, bb, bb};
    #pragma unroll
    for (int kw_ = 0; kw_ < 3; ++kw_) {
      int rowb = (pt*16 + lm + kw_)*148;
      int wrow = (kw_*32 + ot*16 + lm)*148;
      #pragma unroll
      for (int kc = 0; kc < 9; ++kc) {
        s16x4 Aw = *(const s16x4*)&c1s[rowb + kc*16 + lq*4];
        s16x4 Bw = *(const s16x4*)&wt_s[wrow + kc*16 + lq*4];
        acc = mm16(Aw, Bw, acc);
      }
    }
    float* dst = c2 + (size_t)b*9344 + (ot*16 + lm)*292;
    #pragma unroll
    for (int r = 0; r < 4; ++r) {
      int w2l = pt*16 + lq*4 + r;
      if (w2l < 73) dst[w0 + w2l] = fmaxf(acc[r], 0.f);
    }
  }
}

// ---------------- K4: dense1 split-K MFMA
__global__ __launch_bounds__(256) void k_dense1(const float* __restrict__ c2,
    const float* __restrict__ w, float* __restrict__ part) {
  int mt = blockIdx.x & 31;
  int kc = blockIdx.x >> 5;
  int b0 = mt * 16;
  int tid = threadIdx.x;
  int lane = tid & 63; int nt = tid >> 6;
  int lm = lane & 15, lq = lane >> 4;
  int s0 = kc*36 + (kc < 8 ? kc : 8);
  int cnt = 36 + (kc < 8 ? 1 : 0);
  const float* arow = c2 + (size_t)(b0 + lm)*9344;
  const float* brow = w + (size_t)(nt*16 + lm)*9344;
  f32x4 acc = {0.f, 0.f, 0.f, 0.f};
  int koff = s0*16 + lq*4;
  #pragma unroll 4
  for (int i = 0; i < cnt; ++i, koff += 16) {
    s16x4 af = pk4(*(const float4*)(arow + koff));
    s16x4 bf = pk4(*(const float4*)(brow + koff));
    acc = mm16(af, bf, acc);
  }
  float* dst = part + (size_t)kc*32768;
  #pragma unroll
  for (int r = 0; r < 4; ++r)
    dst[(size_t)(b0 + lq*4 + r)*64 + nt*16 + lm] = acc[r];
}

// ---------------- K5: patch embed via MFMA, one block per batch
__global__ __launch_bounds__(256) void k_patch(const float* __restrict__ xs,
    const unsigned short* __restrict__ pwt, const float* __restrict__ pb,
    const float* __restrict__ cls, const float* __restrict__ pos, float* __restrict__ x) {
  int b = blockIdx.x;
  int tid = threadIdx.x;
  int lane = tid & 63; int nt = tid >> 6;
  int lm = lane & 15, lq = lane >> 4;
  __shared__ unsigned short P_s[304*36];

  const float* src = xs + (size_t)b*7500;
  for (int i = tid; i < 304*32; i += 256) {
    int row = i >> 5, k = i & 31;
    unsigned short v = 0;
    if (row >= 1 && row <= 300 && k < 25) v = f2bf(src[(row-1)*25 + k]);
    P_s[row*36 + k] = v;
  }
  __syncthreads();

  int d = nt*16 + lm;
  s16x4 Bf0 = *(const s16x4*)&pwt[d*32 + lq*4];
  s16x4 Bf1 = *(const s16x4*)&pwt[d*32 + 16 + lq*4];
  float pbd = pb[d];
  float clsd = cls[d];
  for (int rt = 0; rt < 19; ++rt) {
    const unsigned short* prow = &P_s[(rt*16 + lm)*36];
    s16x4 A0 = *(const s16x4*)&prow[lq*4];
    s16x4 A1 = *(const s16x4*)&prow[16 + lq*4];
    f32x4 acc = {0.f,0.f,0.f,0.f};
    acc = mm16(A0, Bf0, acc);
    acc = mm16(A1, Bf1, acc);
    #pragma unroll
    for (int r = 0; r < 4; ++r) {
      int t = rt*16 + lq*4 + r;
      if (t < SEQ) {
        float val = acc[r] + pbd + pos[t*64 + d];
        if (t == 0) val = clsd + pos[d];
        x[((size_t)b*SEQ + t)*64 + d] = val;
      }
    }
  }
}

// ---------------- K7: FULL TRANSFORMER LAYER, one block per batch b, 4 waves = 4 heads.
// A: LN1 -> xn_s (once). B: K/V/Q fragments to registers (12 MFMA/tile; xn read once).
// C: attention, FULLY UNROLLED quads (all array indices compile-time -> no scratch);
//    output to LDS (xn_s reused as ao). D: attn-out proj + residual + LN2 + FF.
__global__ __launch_bounds__(256) void k_layer(float* __restrict__ x,
    const float* __restrict__ g, const float* __restrict__ bt,
    const float* __restrict__ qkvw,
    const float* __restrict__ w, const float* __restrict__ bias,
    const float* __restrict__ g2, const float* __restrict__ bt2,
    const float* __restrict__ w1, const float* __restrict__ b1,
    const float* __restrict__ w2, const float* __restrict__ b2) {
  int b = blockIdx.x;
  int tid = threadIdx.x;
  int lane = tid & 63, h = tid >> 6;    // wave = head
  int lm = lane & 15, lq = lane >> 4;
  __shared__ unsigned short xn_s[304*68];  // 41,344 B; reused as ao after phase B

  // ---- phase A: LN1 rows -> xn_s bf16 (once per b)
  for (int rr = tid; rr < 304; rr += 256) {
    int src = rr < 301 ? rr : 300;
    const float4* xp = (const float4*)(x + ((size_t)b*SEQ + src)*64);
    float4 xv[16];
    #pragma unroll
    for (int i = 0; i < 16; ++i) xv[i] = xp[i];
    float m = 0.f;
    #pragma unroll
    for (int i = 0; i < 16; ++i) m += xv[i].x + xv[i].y + xv[i].z + xv[i].w;
    m *= (1.f/64.f);
    float var = 0.f;
    #pragma unroll
    for (int i = 0; i < 16; ++i) {
      float a = xv[i].x-m, bb = xv[i].y-m, c = xv[i].z-m, dd = xv[i].w-m;
      var += a*a + bb*bb + c*c + dd*dd;
    }
    float rs = rsqrtf(var*(1.f/64.f) + 1e-5f);
    const float4* g4 = (const float4*)g;
    const float4* b4 = (const float4*)bt;
    #pragma unroll
    for (int i = 0; i < 16; ++i) {
      float4 gg = g4[i]; float4 bb = b4[i];
      float e0 = (xv[i].x-m)*rs*gg.x + bb.x;
      float e1 = (xv[i].y-m)*rs*gg.y + bb.y;
      float e2 = (xv[i].z-m)*rs*gg.z + bb.z;
      float e3 = (xv[i].w-m)*rs*gg.w + bb.w;
      *(uint2*)&xn_s[rr*68 + i*4] = make_uint2(pkbf(e0, e1), pkbf(e2, e3));
    }
  }

  // ---- per-head weight fragments
  s16x4 WqA[4], WkA[4], WvB[4];
  #pragma unroll
  for (int c = 0; c < 4; ++c) {
    float4 wq = *(const float4*)(qkvw + (size_t)(h*16 + lm)*64 + c*16 + lq*4);
    WqA[c] = pk4f(wq.x*QSCALE, wq.y*QSCALE, wq.z*QSCALE, wq.w*QSCALE);
    WkA[c] = pk4(*(const float4*)(qkvw + (size_t)(64 + h*16 + lm)*64 + c*16 + lq*4));
    WvB[c] = pk4(*(const float4*)(qkvw + (size_t)(128 + h*16 + lm)*64 + c*16 + lq*4));
  }
  __syncthreads();

  // ---- phase B: K (swapped: lane=token), V^T (lane=dim), Q (swapped) to registers
  s16x4 Kreg[19], Vreg[19], Qreg[19];
  #pragma unroll
  for (int rt = 0; rt < 19; ++rt) {
    s16x4 Af[4];
    #pragma unroll
    for (int c = 0; c < 4; ++c)
      Af[c] = *(const s16x4*)&xn_s[(rt*16 + lm)*68 + c*16 + lq*4];
    f32x4 aK = {0.f,0.f,0.f,0.f}, aV = {0.f,0.f,0.f,0.f}, aQ = {0.f,0.f,0.f,0.f};
    #pragma unroll
    for (int c = 0; c < 4; ++c) {
      aK = mm16(WkA[c], Af[c], aK);
      aV = mm16(Af[c], WvB[c], aV);
      aQ = mm16(WqA[c], Af[c], aQ);
    }
    Kreg[rt] = pk4f(aK[0], aK[1], aK[2], aK[3]);
    Vreg[rt] = pk4f(aV[0], aV[1], aV[2], aV[3]);
    Qreg[rt] = pk4f(aQ[0], aQ[1], aQ[2], aQ[3]);
  }
  __syncthreads();   // xn_s reads complete; it now becomes the ao buffer

  // ---- phase C: attention, 4 concurrent qt chains per quad, FULLY UNROLLED
  #pragma unroll
  for (int pi = 0; pi < 5; ++pi) {
    const int nch = (pi < 4) ? 4 : 3;     // 19 = 4*4 + 3
    f32x4 o_[4];
    float l_[4];
    #pragma unroll
    for (int c = 0; c < 4; ++c) { o_[c] = (f32x4){0.f,0.f,0.f,0.f}; l_[c] = 0.f; }
    #pragma unroll
    for (int t = 0; t < 9; ++t) {
      s16x4 kaa = Kreg[2*t];
      s16x4 kab = Kreg[2*t + 1];
      s16x8 vb = cat8(Vreg[2*t], Vreg[2*t + 1]);
      #pragma unroll
      for (int c = 0; c < 4; ++c) {
        if (c >= nch) break;
        f32x4 z = {0.f,0.f,0.f,0.f};
        f32x4 sa = mm16(kaa, Qreg[pi*4 + c], z);
        f32x4 sb = mm16(kab, Qreg[pi*4 + c], z);
        float p0 = EX2(sa[0]), p1 = EX2(sa[1]), p2 = EX2(sa[2]), p3 = EX2(sa[3]);
        float p4 = EX2(sb[0]), p5 = EX2(sb[1]), p6 = EX2(sb[2]), p7 = EX2(sb[3]);
        l_[c] += ((p0 + p1) + (p2 + p3)) + ((p4 + p5) + (p6 + p7));
        s16x8 pa = cat8(pk4f(p0, p1, p2, p3), pk4f(p4, p5, p6, p7));
        o_[c] = mm32(pa, vb, o_[c]);
      }
    }
    { // tail tile kt=18: keys 288..303, mask >= 301
      s16x4 ka = Kreg[18];
      s16x4 vb4 = Vreg[18];
      int kbase = 288 + lq*4;
      #pragma unroll
      for (int c = 0; c < 4; ++c) {
        if (c >= nch) break;
        f32x4 z = {0.f,0.f,0.f,0.f};
        f32x4 st = mm16(ka, Qreg[pi*4 + c], z);
        float p0 = (kbase + 0 < SEQ) ? EX2(st[0]) : 0.f;
        float p1 = (kbase + 1 < SEQ) ? EX2(st[1]) : 0.f;
        float p2 = (kbase + 2 < SEQ) ? EX2(st[2]) : 0.f;
        float p3 = (kbase + 3 < SEQ) ? EX2(st[3]) : 0.f;
        l_[c] += (p0 + p1) + (p2 + p3);
        o_[c] = mm16(pk4f(p0, p1, p2, p3), vb4, o_[c]);
      }
    }
    #pragma unroll
    for (int c = 0; c < 4; ++c) {
      if (c >= nch) break;
      float l = l_[c];
      l += __shfl_xor(l, 16, 64); l += __shfl_xor(l, 32, 64);
      float li = 1.f / l;
      #pragma unroll
      for (int r = 0; r < 4; ++r) {
        int q = (pi*4 + c)*16 + lq*4 + r;
        float lr = __shfl(li, lq*4 + r, 64);
        if (q < SEQ)
          xn_s[q*68 + h*16 + lm] = f2bf(o_[c][r] * lr);
      }
    }
  }
  __syncthreads();   // ao (in LDS) complete for batch b
#if __has_builtin(__builtin_amdgcn_sched_barrier)
  __builtin_amdgcn_sched_barrier(0);   // keep phase-D loads out of phase C (VGPR guard)
#endif

  // ---- phase D: attn-out proj + residual + LN2 + FF + residual (ao from LDS)
  {
    s16x4 Bf[4][4];
    #pragma unroll
    for (int nt = 0; nt < 4; ++nt) {
      #pragma unroll
      for (int c = 0; c < 4; ++c) {
        float4 wf = *(const float4*)(w + (size_t)(nt*16 + lm)*64 + c*16 + lq*4);
        Bf[nt][c] = pk4(wf);
      }
    }
    float biasv[4], gv[4], btv[4], b2v[4];
    float w1r[8][4], w2r[4][8];
    float b1v[8];
    #pragma unroll
    for (int nt = 0; nt < 4; ++nt) {
      biasv[nt] = bias[nt*16 + lm];
      gv[nt]    = g2[nt*16 + lm];
      btv[nt]   = bt2[nt*16 + lm];
      b2v[nt]   = b2[nt*16 + lm];
      #pragma unroll
      for (int t = 0; t < 8; ++t) w2r[nt][t] = w2[(nt*16 + lm)*8 + t];
    }
    #pragma unroll
    for (int t = 0; t < 8; ++t) {
      b1v[t] = b1[t];
      #pragma unroll
      for (int nt = 0; nt < 4; ++nt) w1r[t][nt] = w1[t*64 + nt*16 + lm];
    }

    for (int rt = h; rt < 19; rt += 4) {
      int rsrc = rt*16 + lm; if (rsrc > 300) rsrc = 300;
      const unsigned short* arow = &xn_s[rsrc*68];
      int row0 = rt*16 + lq*4;
      float xpre[4][4];
      #pragma unroll
      for (int r = 0; r < 4; ++r) {
        int row = row0 + r; int rs2 = row > 300 ? 300 : row;
        const float* xr = x + ((size_t)b*SEQ + rs2)*64;
        #pragma unroll
        for (int nt = 0; nt < 4; ++nt) xpre[r][nt] = xr[nt*16 + lm];
      }
      f32x4 acc[4];
      #pragma unroll
      for (int nt = 0; nt < 4; ++nt)
        acc[nt] = (f32x4){biasv[nt], biasv[nt], biasv[nt], biasv[nt]};
      #pragma unroll
      for (int c = 0; c < 4; ++c) {
        s16x4 af = *(const s16x4*)(arow + c*16 + lq*4);
        #pragma unroll
        for (int nt = 0; nt < 4; ++nt) acc[nt] = mm16(af, Bf[nt][c], acc[nt]);
      }
      float v[4][4];
      #pragma unroll
      for (int r = 0; r < 4; ++r)
        #pragma unroll
        for (int nt = 0; nt < 4; ++nt) v[r][nt] = acc[nt][r] + xpre[r][nt];
      #pragma unroll
      for (int r = 0; r < 4; ++r) {
        float s = (v[r][0] + v[r][1]) + (v[r][2] + v[r][3]);
        s += __shfl_xor(s, 1, 64); s += __shfl_xor(s, 2, 64);
        s += __shfl_xor(s, 4, 64); s += __shfl_xor(s, 8, 64);
        float m = s * (1.f/64.f);
        float c0 = v[r][0]-m, c1 = v[r][1]-m, c2 = v[r][2]-m, c3 = v[r][3]-m;
        float s2 = (c0*c0 + c1*c1) + (c2*c2 + c3*c3);
        s2 += __shfl_xor(s2, 1, 64); s2 += __shfl_xor(s2, 2, 64);
        s2 += __shfl_xor(s2, 4, 64); s2 += __shfl_xor(s2, 8, 64);
        float rs = rsqrtf(s2*(1.f/64.f) + 1e-5f);
        float xn0 = c0*rs*gv[0] + btv[0];
        float xn1 = c1*rs*gv[1] + btv[1];
        float xn2 = c2*rs*gv[2] + btv[2];
        float xn3 = c3*rs*gv[3] + btv[3];
        float hg[8];
        #pragma unroll
        for (int t = 0; t < 8; ++t) {
          float p = xn0*w1r[t][0] + xn1*w1r[t][1] + xn2*w1r[t][2] + xn3*w1r[t][3];
          p += __shfl_xor(p, 1, 64); p += __shfl_xor(p, 2, 64);
          p += __shfl_xor(p, 4, 64); p += __shfl_xor(p, 8, 64);
          hg[t] = gelu_f(p + b1v[t]);
        }
        int row = row0 + r;
        if (row < SEQ) {
          float* xw = x + ((size_t)b*SEQ + row)*64;
          #pragma unroll
          for (int nt = 0; nt < 4; ++nt) {
            float o = 0.f;
            #pragma unroll
            for (int t = 0; t < 8; ++t) o += hg[t]*w2r[nt][t];
            xw[nt*16 + lm] = v[r][nt] + o + b2v[nt];
          }
        }
      }
    }
  }
}

// ---------------- K10: head (sums dense1 split-K partials + bias inline)
__global__ __launch_bounds__(128) void k_head(const float* __restrict__ x,
    const float* __restrict__ part, const float* __restrict__ d1b,
    const float* __restrict__ g, const float* __restrict__ bt,
    const float* __restrict__ hw, const float* __restrict__ hb, float* __restrict__ out) {
  int b = blockIdx.x; int t = threadIdx.x; int lane = t & 63; int wv = t >> 6;
  float v;
  if (t < 64) {
    v = x[(size_t)b*SEQ*64 + t];
  } else {
    int o = t - 64;
    float acc = d1b[o];
    #pragma unroll
    for (int kc = 0; kc < 16; ++kc) acc += part[(size_t)kc*32768 + b*64 + o];
    v = acc;
  }
  __shared__ float rbuf[2];
  __shared__ float z_s[128];
  float s = v;
  #pragma unroll
  for (int o = 32; o; o >>= 1) s += __shfl_down(s, o, 64);
  if (lane == 0) rbuf[wv] = s;
  __syncthreads();
  float m = (rbuf[0] + rbuf[1]) * (1.f/128.f);
  __syncthreads();
  float c = v - m;
  float s2 = c*c;
  #pragma unroll
  for (int o = 32; o; o >>= 1) s2 += __shfl_down(s2, o, 64);
  if (lane == 0) rbuf[wv] = s2;
  __syncthreads();
  float var = (rbuf[0] + rbuf[1]) * (1.f/128.f);
  z_s[t] = c * rsqrtf(var + 1e-5f) * g[t] + bt[t];
  __syncthreads();
  if (t < 16) {
    float a = hb[t];
    const float* wr = hw + t*128;
    #pragma unroll 8
    for (int j = 0; j < 128; ++j) a += z_s[j]*wr[j];
    out[(size_t)b*16 + t] = a;
  }
}

extern "C" void kernel_launch(void* const* d_in, const int* in_sizes, int n_in,
                              void* d_out, int out_size, void* d_ws, size_t ws_size,
                              hipStream_t stream) {
  const float* input      = (const float*)d_in[0];
  const float* sse_w      = (const float*)d_in[1];
  const float* sse_b      = (const float*)d_in[2];
  const float* conv1_w    = (const float*)d_in[3];
  const float* conv1_b    = (const float*)d_in[4];
  const float* conv2_w    = (const float*)d_in[5];
  const float* conv2_b    = (const float*)d_in[6];
  const float* dense1_w   = (const float*)d_in[7];
  const float* dense1_b   = (const float*)d_in[8];
  const float* patch_w    = (const float*)d_in[9];
  const float* patch_b    = (const float*)d_in[10];
  const float* cls_token  = (const float*)d_in[11];
  const float* pos_emb    = (const float*)d_in[12];
  const float* ln1_g      = (const float*)d_in[13];
  const float* ln1_b      = (const float*)d_in[14];
  const float* qkv_w      = (const float*)d_in[15];
  const float* attn_out_w = (const float*)d_in[16];
  const float* attn_out_b = (const float*)d_in[17];
  const float* ln2_g      = (const float*)d_in[18];
  const float* ln2_b      = (const float*)d_in[19];
  const float* ff1_w      = (const float*)d_in[20];
  const float* ff1_b      = (const float*)d_in[21];
  const float* ff2_w      = (const float*)d_in[22];
  const float* ff2_b      = (const float*)d_in[23];
  const float* head_ln_g  = (const float*)d_in[24];
  const float* head_ln_b  = (const float*)d_in[25];
  const float* head_w     = (const float*)d_in[26];
  const float* head_b     = (const float*)d_in[27];
  float* out = (float*)d_out;

  float* ws = (float*)d_ws;
  float* xs  = ws;                    // 3,840,000 (dead after k_patch -> reused for part)
  float* part = ws;                   // 16*32768 floats (dense1 partials, after k_patch)
  float* y   = xs + 3840000;          // 32,768 floats region for prep outputs
  unsigned short* wt2g = (unsigned short*)y;            // 96*148 u16
  unsigned short* pwt  = (unsigned short*)(y + 16384);  // 64*32 u16
  float* x   = y + 32768;             // 9,863,168
  float* R   = x + 9863168;           // shared region
  float* c2  = R + 21676032;          // conv phase

  k_prep  <<<56, 256, 0, stream>>>(conv2_w, wt2g);
  k_prep2 <<<8, 256, 0, stream>>>(patch_w, pwt);
  k_sse   <<<NB*25, 64, 0, stream>>>(input, sse_w, sse_b, xs);
  k_conv12<<<NB*4, 256, 0, stream>>>(xs, conv1_w, conv1_b, wt2g, conv2_b, c2);
  k_patch <<<NB, 256, 0, stream>>>(xs, pwt, patch_b, cls_token, pos_emb, x);
  k_dense1<<<512, 256, 0, stream>>>(c2, dense1_w, part);
  for (int i = 0; i < 5; ++i) {
    k_layer<<<NB, 256, 0, stream>>>(x, ln1_g + i*64, ln1_b + i*64,
                 qkv_w + (size_t)i*192*64,
                 attn_out_w + (size_t)i*4096, attn_out_b + i*64,
                 ln2_g + i*64, ln2_b + i*64,
                 ff1_w + (size_t)i*512, ff1_b + i*8, ff2_w + (size_t)i*512, ff2_b + i*64);
  }
  k_head<<<NB, 128, 0, stream>>>(x, part, dense1_b, head_ln_g, head_ln_b, head_w, head_b, out);
}

// Round 20
// 666.798 us; speedup vs baseline: 1.3315x; 1.3315x over previous
//
#include <hip/hip_runtime.h>
#include <cmath>

#define NB 512
#define SEQ 301
// 0.25 * log2(e): folded so attention can use exp2 (native v_exp_f32)
#define QSCALE 0.36067376022f

using f32x4  = __attribute__((ext_vector_type(4))) float;
using s16x4  = __attribute__((ext_vector_type(4))) short;
using s16x8  = __attribute__((ext_vector_type(8))) short;

#if __has_builtin(__builtin_amdgcn_exp2f)
#define EX2(x) __builtin_amdgcn_exp2f(x)
#else
#define EX2(x) exp2f(x)
#endif

__device__ __forceinline__ unsigned short f2bf(float f) {
  unsigned int u = __builtin_bit_cast(unsigned int, f);
  u += 0x7fffu + ((u >> 16) & 1u);
  return (unsigned short)(u >> 16);
}

// pack 2 floats -> bf16x2 (round-half-up) in 3 VALU ops: 2 adds + v_perm
__device__ __forceinline__ unsigned int pkbf(float lo, float hi) {
  unsigned int ulo = __builtin_bit_cast(unsigned int, lo) + 0x8000u;
  unsigned int uhi = __builtin_bit_cast(unsigned int, hi) + 0x8000u;
  return __builtin_amdgcn_perm(uhi, ulo, 0x07060302u);
}

__device__ __forceinline__ s16x4 pk4f(float a, float b, float c, float d) {
  uint2 u = make_uint2(pkbf(a, b), pkbf(c, d));
  return __builtin_bit_cast(s16x4, u);
}

__device__ __forceinline__ s16x4 pk4(float4 v) {
  return pk4f(v.x, v.y, v.z, v.w);
}

__device__ __forceinline__ f32x4 mm16(s16x4 a, s16x4 b, f32x4 c) {
  return __builtin_amdgcn_mfma_f32_16x16x16bf16_1k(a, b, c, 0, 0, 0);
}

__device__ __forceinline__ f32x4 mm32(s16x8 a, s16x8 b, f32x4 c) {
  return __builtin_amdgcn_mfma_f32_16x16x32_bf16(a, b, c, 0, 0, 0);
}

__device__ __forceinline__ s16x8 cat8(s16x4 a, s16x4 b) {
  return __builtin_shufflevector(a, b, 0, 1, 2, 3, 4, 5, 6, 7);
}

// exact-enough gelu: erf via A&S 7.1.26 (|err|<1.5e-7), native exp2
__device__ __forceinline__ float gelu_f(float a) {
  float z = fabsf(a) * 0.70710678f;
  float t = 1.f / (1.f + 0.3275911f * z);
  float poly = t*(0.254829592f + t*(-0.284496736f + t*(1.421413741f +
               t*(-1.453152027f + t*1.061405429f))));
  float e = EX2(-z*z*1.44269504f);
  float erfa = 1.f - poly*e;
  float erfz = copysignf(erfa, a);
  return 0.5f*a*(1.f + erfz);
}

// ---------------- K0a: one-shot conv2 weight reorg -> [kw*32+o2][148] bf16 (pad zero)
__global__ __launch_bounds__(256) void k_prep(const float* __restrict__ w2c,
    unsigned short* __restrict__ wt2g) {
  int i = blockIdx.x*256 + threadIdx.x;
  if (i >= 96*148) return;
  int row = i/148, k = i - row*148;
  int kw_ = row >> 5, o2 = row & 31;
  unsigned short v = 0;
  if (k < 144) {
    int ci = k/9, r_ = k - ci*9;
    v = f2bf(w2c[o2*432 + ci*27 + r_*3 + kw_]);
  }
  wt2g[i] = v;
}

// ---------------- K0b: one-shot patch weight pad -> pwt[64][32] bf16 (k>=25 zero)
__global__ __launch_bounds__(256) void k_prep2(const float* __restrict__ pw,
    unsigned short* __restrict__ pwt) {
  int i = blockIdx.x*256 + threadIdx.x;
  if (i >= 64*32) return;
  int d = i >> 5, k = i & 31;
  pwt[i] = (k < 25) ? f2bf(pw[d*25 + k]) : (unsigned short)0;
}

// ---------------- K1: SSE gate
__global__ __launch_bounds__(64) void k_sse(const float* __restrict__ xin,
    const float* __restrict__ sw, const float* __restrict__ sb, float* __restrict__ xs) {
  int blk = blockIdx.x; int b = blk / 25, p = blk % 25; int lane = threadIdx.x;
  const float* src = xin + (size_t)b*7500 + p*300;
  float s = 0.f;
  for (int c = lane; c < 300; c += 64) s += src[c]*sw[c];
  #pragma unroll
  for (int o = 32; o > 0; o >>= 1) s += __shfl_down(s, o, 64);
  s = __shfl(s, 0, 64);
  float sq = 1.f/(1.f + __expf(-(s + sb[0])));
  float* dst = xs + (size_t)b*7500 + p*300;
  for (int c = lane; c < 300; c += 64) dst[c] = src[c]*sq;
}

// ---------------- K2: fused conv1+conv2 (MFMA, conv1 output in LDS only)
__global__ __launch_bounds__(256) void k_conv12(const float* __restrict__ xs,
    const float* __restrict__ w1c, const float* __restrict__ b1c,
    const unsigned short* __restrict__ wt2g, const float* __restrict__ b2c,
    float* __restrict__ c2) {
  int blk = blockIdx.x; int b = blk >> 2; int chunk = blk & 3;
  int w0 = chunk*73;
  int tid = threadIdx.x;
  int lane = tid & 63, wv = tid >> 6;
  int lm = lane & 15, lq = lane >> 4;
  __shared__ unsigned short xss[32*88];
  __shared__ unsigned short c1s[84*148];
  __shared__ alignas(8) unsigned short wt_s[96*148];

  const float* src = xs + (size_t)b*7500;
  for (int i = tid; i < 2025; i += 256) {
    int p = i/81, c = i - p*81;
    xss[p*88 + c] = f2bf(src[p*300 + w0 + c]);
  }
  for (int i = tid; i < 7*88; i += 256) xss[25*88 + i] = 0;
  for (int i = tid; i < 25*7; i += 256) { int p = i/7, c = 81 + i%7; xss[p*88 + c] = 0; }
  for (int i = tid; i < 9*148; i += 256) c1s[75*148 + i] = 0;
  {
    const uint2* wsrc = (const uint2*)wt2g;
    uint2* wdst = (uint2*)wt_s;
    for (int i = tid; i < 3552; i += 256) wdst[i] = wsrc[i];
  }

  s16x4 Af[4]; int P[4][4]; float bv[4];
  #pragma unroll
  for (int r = 0; r < 4; ++r) bv[r] = b1c[lq*4 + r];
  #pragma unroll
  for (int kc = 0; kc < 4; ++kc) {
    short e[4];
    #pragma unroll
    for (int j = 0; j < 4; ++j) {
      int k = kc*16 + lq*4 + j;
      float wf = (k < 63) ? w1c[lm*63 + k] : 0.f;
      e[j] = (short)f2bf(wf);
      int r_ = k/7, kw_ = k - r_*7;
      int kd = r_/3, kh = r_ - kd*3;
      P[kc][j] = (kd*5 + kh)*88 + kw_;
    }
    s16x4 a; a.x = e[0]; a.y = e[1]; a.z = e[2]; a.w = e[3];
    Af[kc] = a;
  }
  __syncthreads();

  for (int idx = wv; idx < 45; idx += 4) {
    int dh = idx/5, pt = idx - dh*5;
    int d0 = dh/3, h0 = dh - d0*3;
    int base = (d0*5 + h0)*88 + pt*16 + lm;
    f32x4 acc = {bv[0], bv[1], bv[2], bv[3]};
    #pragma unroll
    for (int kc = 0; kc < 4; ++kc) {
      s16x4 Bf;
      Bf.x = (short)xss[base + P[kc][0]];
      Bf.y = (short)xss[base + P[kc][1]];
      Bf.z = (short)xss[base + P[kc][2]];
      Bf.w = (short)xss[base + P[kc][3]];
      acc = mm16(Af[kc], Bf, acc);
    }
    int lw = pt*16 + lm;
    if (lw < 75) {
      unsigned short* dst = c1s + lw*148 + dh;
      #pragma unroll
      for (int r = 0; r < 4; ++r)
        dst[(lq*4 + r)*9] = f2bf(fmaxf(acc[r], 0.f));
    }
  }
  __syncthreads();

  float bvo0 = b2c[lm], bvo1 = b2c[16 + lm];
  for (int task = wv; task < 10; task += 4) {
    int pt = task >> 1, ot = task & 1;
    float bb = ot ? bvo1 : bvo0;
    f32x4 acc = {bb, bb, bb, bb};
    #pragma unroll
    for (int kw_ = 0; kw_ < 3; ++kw_) {
      int rowb = (pt*16 + lm + kw_)*148;
      int wrow = (kw_*32 + ot*16 + lm)*148;
      #pragma unroll
      for (int kc = 0; kc < 9; ++kc) {
        s16x4 Aw = *(const s16x4*)&c1s[rowb + kc*16 + lq*4];
        s16x4 Bw = *(const s16x4*)&wt_s[wrow + kc*16 + lq*4];
        acc = mm16(Aw, Bw, acc);
      }
    }
    float* dst = c2 + (size_t)b*9344 + (ot*16 + lm)*292;
    #pragma unroll
    for (int r = 0; r < 4; ++r) {
      int w2l = pt*16 + lq*4 + r;
      if (w2l < 73) dst[w0 + w2l] = fmaxf(acc[r], 0.f);
    }
  }
}

// ---------------- K4: dense1 split-K MFMA
__global__ __launch_bounds__(256) void k_dense1(const float* __restrict__ c2,
    const float* __restrict__ w, float* __restrict__ part) {
  int mt = blockIdx.x & 31;
  int kc = blockIdx.x >> 5;
  int b0 = mt * 16;
  int tid = threadIdx.x;
  int lane = tid & 63; int nt = tid >> 6;
  int lm = lane & 15, lq = lane >> 4;
  int s0 = kc*36 + (kc < 8 ? kc : 8);
  int cnt = 36 + (kc < 8 ? 1 : 0);
  const float* arow = c2 + (size_t)(b0 + lm)*9344;
  const float* brow = w + (size_t)(nt*16 + lm)*9344;
  f32x4 acc = {0.f, 0.f, 0.f, 0.f};
  int koff = s0*16 + lq*4;
  #pragma unroll 4
  for (int i = 0; i < cnt; ++i, koff += 16) {
    s16x4 af = pk4(*(const float4*)(arow + koff));
    s16x4 bf = pk4(*(const float4*)(brow + koff));
    acc = mm16(af, bf, acc);
  }
  float* dst = part + (size_t)kc*32768;
  #pragma unroll
  for (int r = 0; r < 4; ++r)
    dst[(size_t)(b0 + lq*4 + r)*64 + nt*16 + lm] = acc[r];
}

// ---------------- K5: patch embed via MFMA, one block per batch
__global__ __launch_bounds__(256) void k_patch(const float* __restrict__ xs,
    const unsigned short* __restrict__ pwt, const float* __restrict__ pb,
    const float* __restrict__ cls, const float* __restrict__ pos, float* __restrict__ x) {
  int b = blockIdx.x;
  int tid = threadIdx.x;
  int lane = tid & 63; int nt = tid >> 6;
  int lm = lane & 15, lq = lane >> 4;
  __shared__ unsigned short P_s[304*36];

  const float* src = xs + (size_t)b*7500;
  for (int i = tid; i < 304*32; i += 256) {
    int row = i >> 5, k = i & 31;
    unsigned short v = 0;
    if (row >= 1 && row <= 300 && k < 25) v = f2bf(src[(row-1)*25 + k]);
    P_s[row*36 + k] = v;
  }
  __syncthreads();

  int d = nt*16 + lm;
  s16x4 Bf0 = *(const s16x4*)&pwt[d*32 + lq*4];
  s16x4 Bf1 = *(const s16x4*)&pwt[d*32 + 16 + lq*4];
  float pbd = pb[d];
  float clsd = cls[d];
  for (int rt = 0; rt < 19; ++rt) {
    const unsigned short* prow = &P_s[(rt*16 + lm)*36];
    s16x4 A0 = *(const s16x4*)&prow[lq*4];
    s16x4 A1 = *(const s16x4*)&prow[16 + lq*4];
    f32x4 acc = {0.f,0.f,0.f,0.f};
    acc = mm16(A0, Bf0, acc);
    acc = mm16(A1, Bf1, acc);
    #pragma unroll
    for (int r = 0; r < 4; ++r) {
      int t = rt*16 + lq*4 + r;
      if (t < SEQ) {
        float val = acc[r] + pbd + pos[t*64 + d];
        if (t == 0) val = clsd + pos[d];
        x[((size_t)b*SEQ + t)*64 + d] = val;
      }
    }
  }
}

// ---------------- K7: FULL TRANSFORMER LAYER, one block per batch b, 4 waves = 4 heads.
// A: LN1 -> xn_s (once). B: K/V fragments to registers (Q recomputed per pair).
// C: attention in 10 lockstep pairs; pair pi reads Q from xn rows [32pi,32pi+32),
//    barrier, then writes ao INTO THOSE SAME xn_s ROWS (each head owns 16 cols;
//    later pairs read strictly higher rows -> race-free). D: proj+LN2+FF from LDS ao.
__global__ __launch_bounds__(256) void k_layer(float* __restrict__ x,
    const float* __restrict__ g, const float* __restrict__ bt,
    const float* __restrict__ qkvw,
    const float* __restrict__ w, const float* __restrict__ bias,
    const float* __restrict__ g2, const float* __restrict__ bt2,
    const float* __restrict__ w1, const float* __restrict__ b1,
    const float* __restrict__ w2, const float* __restrict__ b2) {
  int b = blockIdx.x;
  int tid = threadIdx.x;
  int lane = tid & 63, h = tid >> 6;    // wave = head
  int lm = lane & 15, lq = lane >> 4;
  __shared__ unsigned short xn_s[304*68];  // 41,344 B; rows become ao after their pair

  // ---- phase A: LN1 rows -> xn_s bf16 (once per b)
  for (int rr = tid; rr < 304; rr += 256) {
    int src = rr < 301 ? rr : 300;
    const float4* xp = (const float4*)(x + ((size_t)b*SEQ + src)*64);
    float4 xv[16];
    #pragma unroll
    for (int i = 0; i < 16; ++i) xv[i] = xp[i];
    float m = 0.f;
    #pragma unroll
    for (int i = 0; i < 16; ++i) m += xv[i].x + xv[i].y + xv[i].z + xv[i].w;
    m *= (1.f/64.f);
    float var = 0.f;
    #pragma unroll
    for (int i = 0; i < 16; ++i) {
      float a = xv[i].x-m, bb = xv[i].y-m, c = xv[i].z-m, dd = xv[i].w-m;
      var += a*a + bb*bb + c*c + dd*dd;
    }
    float rs = rsqrtf(var*(1.f/64.f) + 1e-5f);
    const float4* g4 = (const float4*)g;
    const float4* b4 = (const float4*)bt;
    #pragma unroll
    for (int i = 0; i < 16; ++i) {
      float4 gg = g4[i]; float4 bb = b4[i];
      float e0 = (xv[i].x-m)*rs*gg.x + bb.x;
      float e1 = (xv[i].y-m)*rs*gg.y + bb.y;
      float e2 = (xv[i].z-m)*rs*gg.z + bb.z;
      float e3 = (xv[i].w-m)*rs*gg.w + bb.w;
      *(uint2*)&xn_s[rr*68 + i*4] = make_uint2(pkbf(e0, e1), pkbf(e2, e3));
    }
  }

  // ---- per-head weight fragments
  s16x4 WqA[4], WkA[4], WvB[4];
  #pragma unroll
  for (int c = 0; c < 4; ++c) {
    float4 wq = *(const float4*)(qkvw + (size_t)(h*16 + lm)*64 + c*16 + lq*4);
    WqA[c] = pk4f(wq.x*QSCALE, wq.y*QSCALE, wq.z*QSCALE, wq.w*QSCALE);
    WkA[c] = pk4(*(const float4*)(qkvw + (size_t)(64 + h*16 + lm)*64 + c*16 + lq*4));
    WvB[c] = pk4(*(const float4*)(qkvw + (size_t)(128 + h*16 + lm)*64 + c*16 + lq*4));
  }
  __syncthreads();

  // ---- phase B: K (swapped: lane=token) and V^T (lane=dim) into registers
  s16x4 Kreg[19], Vreg[19];
  #pragma unroll
  for (int rt = 0; rt < 19; ++rt) {
    s16x4 Af[4];
    #pragma unroll
    for (int c = 0; c < 4; ++c)
      Af[c] = *(const s16x4*)&xn_s[(rt*16 + lm)*68 + c*16 + lq*4];
    f32x4 aK = {0.f,0.f,0.f,0.f}, aV = {0.f,0.f,0.f,0.f};
    #pragma unroll
    for (int c = 0; c < 4; ++c) {
      aK = mm16(WkA[c], Af[c], aK);
      aV = mm16(Af[c], WvB[c], aV);
    }
    Kreg[rt] = pk4f(aK[0], aK[1], aK[2], aK[3]);
    Vreg[rt] = pk4f(aV[0], aV[1], aV[2], aV[3]);
  }

  // ---- phase C: attention, 10 lockstep pairs; ao overwrites xn_s rows of the pair
  for (int pi = 0; pi < 10; ++pi) {
    int qt0 = 2*pi;
    int qt1 = 2*pi + 1;
    bool two = (qt1 < 19);
    int qt1c = two ? qt1 : qt0;
    // read this pair's Q rows from xn_s (all heads), project to fragments
    s16x4 qb0, qb1;
    {
      s16x4 Af0[4], Af1[4];
      #pragma unroll
      for (int c = 0; c < 4; ++c) {
        Af0[c] = *(const s16x4*)&xn_s[(qt0*16 + lm)*68 + c*16 + lq*4];
        Af1[c] = *(const s16x4*)&xn_s[(qt1c*16 + lm)*68 + c*16 + lq*4];
      }
      f32x4 a0 = {0.f,0.f,0.f,0.f}, a1 = {0.f,0.f,0.f,0.f};
      #pragma unroll
      for (int c = 0; c < 4; ++c) {
        a0 = mm16(WqA[c], Af0[c], a0);
        a1 = mm16(WqA[c], Af1[c], a1);
      }
      qb0 = pk4f(a0[0], a0[1], a0[2], a0[3]);
      qb1 = pk4f(a1[0], a1[1], a1[2], a1[3]);
    }
    __syncthreads();   // all heads done reading pair-pi rows; writes may begin
    f32x4 o0 = {0.f,0.f,0.f,0.f}, o1 = {0.f,0.f,0.f,0.f};
    float l0 = 0.f, l1 = 0.f;
    #pragma unroll
    for (int t = 0; t < 9; ++t) {
      s16x4 kaa = Kreg[2*t];
      s16x4 kab = Kreg[2*t + 1];
      s16x8 vb = cat8(Vreg[2*t], Vreg[2*t + 1]);
      f32x4 z = {0.f,0.f,0.f,0.f};
      f32x4 s0a = mm16(kaa, qb0, z);
      f32x4 s0b = mm16(kab, qb0, z);
      f32x4 s1a = mm16(kaa, qb1, z);
      f32x4 s1b = mm16(kab, qb1, z);
      float p00 = EX2(s0a[0]), p01 = EX2(s0a[1]), p02 = EX2(s0a[2]), p03 = EX2(s0a[3]);
      float p04 = EX2(s0b[0]), p05 = EX2(s0b[1]), p06 = EX2(s0b[2]), p07 = EX2(s0b[3]);
      float p10 = EX2(s1a[0]), p11 = EX2(s1a[1]), p12 = EX2(s1a[2]), p13 = EX2(s1a[3]);
      float p14 = EX2(s1b[0]), p15 = EX2(s1b[1]), p16 = EX2(s1b[2]), p17 = EX2(s1b[3]);
      l0 += ((p00 + p01) + (p02 + p03)) + ((p04 + p05) + (p06 + p07));
      l1 += ((p10 + p11) + (p12 + p13)) + ((p14 + p15) + (p16 + p17));
      s16x8 pa0 = cat8(pk4f(p00, p01, p02, p03), pk4f(p04, p05, p06, p07));
      s16x8 pa1 = cat8(pk4f(p10, p11, p12, p13), pk4f(p14, p15, p16, p17));
      o0 = mm32(pa0, vb, o0);
      o1 = mm32(pa1, vb, o1);
    }
    { // tail tile kt=18: keys 288..303, mask >= 301
      s16x4 ka = Kreg[18];
      s16x4 vb = Vreg[18];
      f32x4 z = {0.f,0.f,0.f,0.f};
      f32x4 st0 = mm16(ka, qb0, z);
      f32x4 st1 = mm16(ka, qb1, z);
      int kbase = 288 + lq*4;
      float p00 = (kbase + 0 < SEQ) ? EX2(st0[0]) : 0.f;
      float p01 = (kbase + 1 < SEQ) ? EX2(st0[1]) : 0.f;
      float p02 = (kbase + 2 < SEQ) ? EX2(st0[2]) : 0.f;
      float p03 = (kbase + 3 < SEQ) ? EX2(st0[3]) : 0.f;
      float p10 = (kbase + 0 < SEQ) ? EX2(st1[0]) : 0.f;
      float p11 = (kbase + 1 < SEQ) ? EX2(st1[1]) : 0.f;
      float p12 = (kbase + 2 < SEQ) ? EX2(st1[2]) : 0.f;
      float p13 = (kbase + 3 < SEQ) ? EX2(st1[3]) : 0.f;
      l0 += (p00 + p01) + (p02 + p03);
      l1 += (p10 + p11) + (p12 + p13);
      s16x4 pa0 = pk4f(p00, p01, p02, p03);
      s16x4 pa1 = pk4f(p10, p11, p12, p13);
      o0 = mm16(pa0, vb, o0);
      o1 = mm16(pa1, vb, o1);
    }
    l0 += __shfl_xor(l0, 16, 64); l0 += __shfl_xor(l0, 32, 64);
    l1 += __shfl_xor(l1, 16, 64); l1 += __shfl_xor(l1, 32, 64);
    float li0 = 1.f / l0;
    float li1 = 1.f / l1;
    #pragma unroll
    for (int r = 0; r < 4; ++r) {
      int q0 = qt0*16 + lq*4 + r;
      float lr0 = __shfl(li0, lq*4 + r, 64);
      if (q0 < SEQ) xn_s[q0*68 + h*16 + lm] = f2bf(o0[r] * lr0);
      if (two) {
        int q1 = qt1*16 + lq*4 + r;
        float lr1 = __shfl(li1, lq*4 + r, 64);
        if (q1 < SEQ) xn_s[q1*68 + h*16 + lm] = f2bf(o1[r] * lr1);
      }
    }
  }
  __syncthreads();   // ao (in LDS, xn_s) complete for batch b
#if __has_builtin(__builtin_amdgcn_sched_barrier)
  __builtin_amdgcn_sched_barrier(0);   // keep phase-D loads out of phase C
#endif

  // ---- phase D: attn-out proj + residual + LN2 + FF + residual (ao from LDS)
  {
    s16x4 Bf[4][4];
    #pragma unroll
    for (int nt = 0; nt < 4; ++nt) {
      #pragma unroll
      for (int c = 0; c < 4; ++c) {
        float4 wf = *(const float4*)(w + (size_t)(nt*16 + lm)*64 + c*16 + lq*4);
        Bf[nt][c] = pk4(wf);
      }
    }
    float biasv[4], gv[4], btv[4], b2v[4];
    float w1r[8][4], w2r[4][8];
    float b1v[8];
    #pragma unroll
    for (int nt = 0; nt < 4; ++nt) {
      biasv[nt] = bias[nt*16 + lm];
      gv[nt]    = g2[nt*16 + lm];
      btv[nt]   = bt2[nt*16 + lm];
      b2v[nt]   = b2[nt*16 + lm];
      #pragma unroll
      for (int t = 0; t < 8; ++t) w2r[nt][t] = w2[(nt*16 + lm)*8 + t];
    }
    #pragma unroll
    for (int t = 0; t < 8; ++t) {
      b1v[t] = b1[t];
      #pragma unroll
      for (int nt = 0; nt < 4; ++nt) w1r[t][nt] = w1[t*64 + nt*16 + lm];
    }

    for (int rt = h; rt < 19; rt += 4) {
      int rsrc = rt*16 + lm; if (rsrc > 300) rsrc = 300;
      const unsigned short* arow = &xn_s[rsrc*68];
      int row0 = rt*16 + lq*4;
      float xpre[4][4];
      #pragma unroll
      for (int r = 0; r < 4; ++r) {
        int row = row0 + r; int rs2 = row > 300 ? 300 : row;
        const float* xr = x + ((size_t)b*SEQ + rs2)*64;
        #pragma unroll
        for (int nt = 0; nt < 4; ++nt) xpre[r][nt] = xr[nt*16 + lm];
      }
      f32x4 acc[4];
      #pragma unroll
      for (int nt = 0; nt < 4; ++nt)
        acc[nt] = (f32x4){biasv[nt], biasv[nt], biasv[nt], biasv[nt]};
      #pragma unroll
      for (int c = 0; c < 4; ++c) {
        s16x4 af = *(const s16x4*)(arow + c*16 + lq*4);
        #pragma unroll
        for (int nt = 0; nt < 4; ++nt) acc[nt] = mm16(af, Bf[nt][c], acc[nt]);
      }
      float v[4][4];
      #pragma unroll
      for (int r = 0; r < 4; ++r)
        #pragma unroll
        for (int nt = 0; nt < 4; ++nt) v[r][nt] = acc[nt][r] + xpre[r][nt];
      #pragma unroll
      for (int r = 0; r < 4; ++r) {
        float s = (v[r][0] + v[r][1]) + (v[r][2] + v[r][3]);
        s += __shfl_xor(s, 1, 64); s += __shfl_xor(s, 2, 64);
        s += __shfl_xor(s, 4, 64); s += __shfl_xor(s, 8, 64);
        float m = s * (1.f/64.f);
        float c0 = v[r][0]-m, c1 = v[r][1]-m, c2 = v[r][2]-m, c3 = v[r][3]-m;
        float s2 = (c0*c0 + c1*c1) + (c2*c2 + c3*c3);
        s2 += __shfl_xor(s2, 1, 64); s2 += __shfl_xor(s2, 2, 64);
        s2 += __shfl_xor(s2, 4, 64); s2 += __shfl_xor(s2, 8, 64);
        float rs = rsqrtf(s2*(1.f/64.f) + 1e-5f);
        float xn0 = c0*rs*gv[0] + btv[0];
        float xn1 = c1*rs*gv[1] + btv[1];
        float xn2 = c2*rs*gv[2] + btv[2];
        float xn3 = c3*rs*gv[3] + btv[3];
        float hg[8];
        #pragma unroll
        for (int t = 0; t < 8; ++t) {
          float p = xn0*w1r[t][0] + xn1*w1r[t][1] + xn2*w1r[t][2] + xn3*w1r[t][3];
          p += __shfl_xor(p, 1, 64); p += __shfl_xor(p, 2, 64);
          p += __shfl_xor(p, 4, 64); p += __shfl_xor(p, 8, 64);
          hg[t] = gelu_f(p + b1v[t]);
        }
        int row = row0 + r;
        if (row < SEQ) {
          float* xw = x + ((size_t)b*SEQ + row)*64;
          #pragma unroll
          for (int nt = 0; nt < 4; ++nt) {
            float o = 0.f;
            #pragma unroll
            for (int t = 0; t < 8; ++t) o += hg[t]*w2r[nt][t];
            xw[nt*16 + lm] = v[r][nt] + o + b2v[nt];
          }
        }
      }
    }
  }
}

// ---------------- K10: head (sums dense1 split-K partials + bias inline)
__global__ __launch_bounds__(128) void k_head(const float* __restrict__ x,
    const float* __restrict__ part, const float* __restrict__ d1b,
    const float* __restrict__ g, const float* __restrict__ bt,
    const float* __restrict__ hw, const float* __restrict__ hb, float* __restrict__ out) {
  int b = blockIdx.x; int t = threadIdx.x; int lane = t & 63; int wv = t >> 6;
  float v;
  if (t < 64) {
    v = x[(size_t)b*SEQ*64 + t];
  } else {
    int o = t - 64;
    float acc = d1b[o];
    #pragma unroll
    for (int kc = 0; kc < 16; ++kc) acc += part[(size_t)kc*32768 + b*64 + o];
    v = acc;
  }
  __shared__ float rbuf[2];
  __shared__ float z_s[128];
  float s = v;
  #pragma unroll
  for (int o = 32; o; o >>= 1) s += __shfl_down(s, o, 64);
  if (lane == 0) rbuf[wv] = s;
  __syncthreads();
  float m = (rbuf[0] + rbuf[1]) * (1.f/128.f);
  __syncthreads();
  float c = v - m;
  float s2 = c*c;
  #pragma unroll
  for (int o = 32; o; o >>= 1) s2 += __shfl_down(s2, o, 64);
  if (lane == 0) rbuf[wv] = s2;
  __syncthreads();
  float var = (rbuf[0] + rbuf[1]) * (1.f/128.f);
  z_s[t] = c * rsqrtf(var + 1e-5f) * g[t] + bt[t];
  __syncthreads();
  if (t < 16) {
    float a = hb[t];
    const float* wr = hw + t*128;
    #pragma unroll 8
    for (int j = 0; j < 128; ++j) a += z_s[j]*wr[j];
    out[(size_t)b*16 + t] = a;
  }
}

extern "C" void kernel_launch(void* const* d_in, const int* in_sizes, int n_in,
                              void* d_out, int out_size, void* d_ws, size_t ws_size,
                              hipStream_t stream) {
  const float* input      = (const float*)d_in[0];
  const float* sse_w      = (const float*)d_in[1];
  const float* sse_b      = (const float*)d_in[2];
  const float* conv1_w    = (const float*)d_in[3];
  const float* conv1_b    = (const float*)d_in[4];
  const float* conv2_w    = (const float*)d_in[5];
  const float* conv2_b    = (const float*)d_in[6];
  const float* dense1_w   = (const float*)d_in[7];
  const float* dense1_b   = (const float*)d_in[8];
  const float* patch_w    = (const float*)d_in[9];
  const float* patch_b    = (const float*)d_in[10];
  const float* cls_token  = (const float*)d_in[11];
  const float* pos_emb    = (const float*)d_in[12];
  const float* ln1_g      = (const float*)d_in[13];
  const float* ln1_b      = (const float*)d_in[14];
  const float* qkv_w      = (const float*)d_in[15];
  const float* attn_out_w = (const float*)d_in[16];
  const float* attn_out_b = (const float*)d_in[17];
  const float* ln2_g      = (const float*)d_in[18];
  const float* ln2_b      = (const float*)d_in[19];
  const float* ff1_w      = (const float*)d_in[20];
  const float* ff1_b      = (const float*)d_in[21];
  const float* ff2_w      = (const float*)d_in[22];
  const float* ff2_b      = (const float*)d_in[23];
  const float* head_ln_g  = (const float*)d_in[24];
  const float* head_ln_b  = (const float*)d_in[25];
  const float* head_w     = (const float*)d_in[26];
  const float* head_b     = (const float*)d_in[27];
  float* out = (float*)d_out;

  float* ws = (float*)d_ws;
  float* xs  = ws;                    // 3,840,000 (dead after k_patch -> reused for part)
  float* part = ws;                   // 16*32768 floats (dense1 partials, after k_patch)
  float* y   = xs + 3840000;          // 32,768 floats region for prep outputs
  unsigned short* wt2g = (unsigned short*)y;            // 96*148 u16
  unsigned short* pwt  = (unsigned short*)(y + 16384);  // 64*32 u16
  float* x   = y + 32768;             // 9,863,168
  float* R   = x + 9863168;           // shared region
  float* c2  = R + 21676032;          // conv phase

  k_prep  <<<56, 256, 0, stream>>>(conv2_w, wt2g);
  k_prep2 <<<8, 256, 0, stream>>>(patch_w, pwt);
  k_sse   <<<NB*25, 64, 0, stream>>>(input, sse_w, sse_b, xs);
  k_conv12<<<NB*4, 256, 0, stream>>>(xs, conv1_w, conv1_b, wt2g, conv2_b, c2);
  k_patch <<<NB, 256, 0, stream>>>(xs, pwt, patch_b, cls_token, pos_emb, x);
  k_dense1<<<512, 256, 0, stream>>>(c2, dense1_w, part);
  for (int i = 0; i < 5; ++i) {
    k_layer<<<NB, 256, 0, stream>>>(x, ln1_g + i*64, ln1_b + i*64,
                 qkv_w + (size_t)i*192*64,
                 attn_out_w + (size_t)i*4096, attn_out_b + i*64,
                 ln2_g + i*64, ln2_b + i*64,
                 ff1_w + (size_t)i*512, ff1_b + i*8, ff2_w + (size_t)i*512, ff2_b + i*64);
  }
  k_head<<<NB, 128, 0, stream>>>(x, part, dense1_b, head_ln_g, head_ln_b, head_w, head_b, out);
}

// Round 21
// 658.678 us; speedup vs baseline: 1.3479x; 1.0123x over previous
//
#include <hip/hip_runtime.h>
#include <cmath>

#define NB 512
#define SEQ 301
// 0.25 * log2(e): folded so attention can use exp2 (native v_exp_f32)
#define QSCALE 0.36067376022f

using f32x4  = __attribute__((ext_vector_type(4))) float;
using s16x4  = __attribute__((ext_vector_type(4))) short;
using s16x8  = __attribute__((ext_vector_type(8))) short;

#if __has_builtin(__builtin_amdgcn_exp2f)
#define EX2(x) __builtin_amdgcn_exp2f(x)
#else
#define EX2(x) exp2f(x)
#endif

__device__ __forceinline__ unsigned short f2bf(float f) {
  unsigned int u = __builtin_bit_cast(unsigned int, f);
  u += 0x7fffu + ((u >> 16) & 1u);
  return (unsigned short)(u >> 16);
}

// pack 2 floats -> bf16x2 (round-half-up) in 3 VALU ops: 2 adds + v_perm
__device__ __forceinline__ unsigned int pkbf(float lo, float hi) {
  unsigned int ulo = __builtin_bit_cast(unsigned int, lo) + 0x8000u;
  unsigned int uhi = __builtin_bit_cast(unsigned int, hi) + 0x8000u;
  return __builtin_amdgcn_perm(uhi, ulo, 0x07060302u);
}

__device__ __forceinline__ s16x4 pk4f(float a, float b, float c, float d) {
  uint2 u = make_uint2(pkbf(a, b), pkbf(c, d));
  return __builtin_bit_cast(s16x4, u);
}

__device__ __forceinline__ s16x4 pk4(float4 v) {
  return pk4f(v.x, v.y, v.z, v.w);
}

__device__ __forceinline__ f32x4 mm16(s16x4 a, s16x4 b, f32x4 c) {
  return __builtin_amdgcn_mfma_f32_16x16x16bf16_1k(a, b, c, 0, 0, 0);
}

__device__ __forceinline__ f32x4 mm32(s16x8 a, s16x8 b, f32x4 c) {
  return __builtin_amdgcn_mfma_f32_16x16x32_bf16(a, b, c, 0, 0, 0);
}

__device__ __forceinline__ s16x8 cat8(s16x4 a, s16x4 b) {
  return __builtin_shufflevector(a, b, 0, 1, 2, 3, 4, 5, 6, 7);
}

// exact-enough gelu: erf via A&S 7.1.26 (|err|<1.5e-7), native exp2
__device__ __forceinline__ float gelu_f(float a) {
  float z = fabsf(a) * 0.70710678f;
  float t = 1.f / (1.f + 0.3275911f * z);
  float poly = t*(0.254829592f + t*(-0.284496736f + t*(1.421413741f +
               t*(-1.453152027f + t*1.061405429f))));
  float e = EX2(-z*z*1.44269504f);
  float erfa = 1.f - poly*e;
  float erfz = copysignf(erfa, a);
  return 0.5f*a*(1.f + erfz);
}

// ---------------- K0a: one-shot conv2 weight reorg -> [kw*32+o2][148] bf16 (pad zero)
__global__ __launch_bounds__(256) void k_prep(const float* __restrict__ w2c,
    unsigned short* __restrict__ wt2g) {
  int i = blockIdx.x*256 + threadIdx.x;
  if (i >= 96*148) return;
  int row = i/148, k = i - row*148;
  int kw_ = row >> 5, o2 = row & 31;
  unsigned short v = 0;
  if (k < 144) {
    int ci = k/9, r_ = k - ci*9;
    v = f2bf(w2c[o2*432 + ci*27 + r_*3 + kw_]);
  }
  wt2g[i] = v;
}

// ---------------- K0b: one-shot patch weight pad -> pwt[64][32] bf16 (k>=25 zero)
__global__ __launch_bounds__(256) void k_prep2(const float* __restrict__ pw,
    unsigned short* __restrict__ pwt) {
  int i = blockIdx.x*256 + threadIdx.x;
  if (i >= 64*32) return;
  int d = i >> 5, k = i & 31;
  pwt[i] = (k < 25) ? f2bf(pw[d*25 + k]) : (unsigned short)0;
}

// ---------------- K1: SSE gate
__global__ __launch_bounds__(64) void k_sse(const float* __restrict__ xin,
    const float* __restrict__ sw, const float* __restrict__ sb, float* __restrict__ xs) {
  int blk = blockIdx.x; int b = blk / 25, p = blk % 25; int lane = threadIdx.x;
  const float* src = xin + (size_t)b*7500 + p*300;
  float s = 0.f;
  for (int c = lane; c < 300; c += 64) s += src[c]*sw[c];
  #pragma unroll
  for (int o = 32; o > 0; o >>= 1) s += __shfl_down(s, o, 64);
  s = __shfl(s, 0, 64);
  float sq = 1.f/(1.f + __expf(-(s + sb[0])));
  float* dst = xs + (size_t)b*7500 + p*300;
  for (int c = lane; c < 300; c += 64) dst[c] = src[c]*sq;
}

// ---------------- K2: fused conv1+conv2 (MFMA, conv1 output in LDS only)
__global__ __launch_bounds__(256) void k_conv12(const float* __restrict__ xs,
    const float* __restrict__ w1c, const float* __restrict__ b1c,
    const unsigned short* __restrict__ wt2g, const float* __restrict__ b2c,
    float* __restrict__ c2) {
  int blk = blockIdx.x; int b = blk >> 2; int chunk = blk & 3;
  int w0 = chunk*73;
  int tid = threadIdx.x;
  int lane = tid & 63, wv = tid >> 6;
  int lm = lane & 15, lq = lane >> 4;
  __shared__ unsigned short xss[32*88];
  __shared__ unsigned short c1s[84*148];
  __shared__ alignas(8) unsigned short wt_s[96*148];

  const float* src = xs + (size_t)b*7500;
  for (int i = tid; i < 2025; i += 256) {
    int p = i/81, c = i - p*81;
    xss[p*88 + c] = f2bf(src[p*300 + w0 + c]);
  }
  for (int i = tid; i < 7*88; i += 256) xss[25*88 + i] = 0;
  for (int i = tid; i < 25*7; i += 256) { int p = i/7, c = 81 + i%7; xss[p*88 + c] = 0; }
  for (int i = tid; i < 9*148; i += 256) c1s[75*148 + i] = 0;
  {
    const uint2* wsrc = (const uint2*)wt2g;
    uint2* wdst = (uint2*)wt_s;
    for (int i = tid; i < 3552; i += 256) wdst[i] = wsrc[i];
  }

  s16x4 Af[4]; int P[4][4]; float bv[4];
  #pragma unroll
  for (int r = 0; r < 4; ++r) bv[r] = b1c[lq*4 + r];
  #pragma unroll
  for (int kc = 0; kc < 4; ++kc) {
    short e[4];
    #pragma unroll
    for (int j = 0; j < 4; ++j) {
      int k = kc*16 + lq*4 + j;
      float wf = (k < 63) ? w1c[lm*63 + k] : 0.f;
      e[j] = (short)f2bf(wf);
      int r_ = k/7, kw_ = k - r_*7;
      int kd = r_/3, kh = r_ - kd*3;
      P[kc][j] = (kd*5 + kh)*88 + kw_;
    }
    s16x4 a; a.x = e[0]; a.y = e[1]; a.z = e[2]; a.w = e[3];
    Af[kc] = a;
  }
  __syncthreads();

  for (int idx = wv; idx < 45; idx += 4) {
    int dh = idx/5, pt = idx - dh*5;
    int d0 = dh/3, h0 = dh - d0*3;
    int base = (d0*5 + h0)*88 + pt*16 + lm;
    f32x4 acc = {bv[0], bv[1], bv[2], bv[3]};
    #pragma unroll
    for (int kc = 0; kc < 4; ++kc) {
      s16x4 Bf;
      Bf.x = (short)xss[base + P[kc][0]];
      Bf.y = (short)xss[base + P[kc][1]];
      Bf.z = (short)xss[base + P[kc][2]];
      Bf.w = (short)xss[base + P[kc][3]];
      acc = mm16(Af[kc], Bf, acc);
    }
    int lw = pt*16 + lm;
    if (lw < 75) {
      unsigned short* dst = c1s + lw*148 + dh;
      #pragma unroll
      for (int r = 0; r < 4; ++r)
        dst[(lq*4 + r)*9] = f2bf(fmaxf(acc[r], 0.f));
    }
  }
  __syncthreads();

  float bvo0 = b2c[lm], bvo1 = b2c[16 + lm];
  for (int task = wv; task < 10; task += 4) {
    int pt = task >> 1, ot = task & 1;
    float bb = ot ? bvo1 : bvo0;
    f32x4 acc = {bb, bb, bb, bb};
    #pragma unroll
    for (int kw_ = 0; kw_ < 3; ++kw_) {
      int rowb = (pt*16 + lm + kw_)*148;
      int wrow = (kw_*32 + ot*16 + lm)*148;
      #pragma unroll
      for (int kc = 0; kc < 9; ++kc) {
        s16x4 Aw = *(const s16x4*)&c1s[rowb + kc*16 + lq*4];
        s16x4 Bw = *(const s16x4*)&wt_s[wrow + kc*16 + lq*4];
        acc = mm16(Aw, Bw, acc);
      }
    }
    float* dst = c2 + (size_t)b*9344 + (ot*16 + lm)*292;
    #pragma unroll
    for (int r = 0; r < 4; ++r) {
      int w2l = pt*16 + lq*4 + r;
      if (w2l < 73) dst[w0 + w2l] = fmaxf(acc[r], 0.f);
    }
  }
}

// ---------------- K4: dense1 split-K MFMA
__global__ __launch_bounds__(256) void k_dense1(const float* __restrict__ c2,
    const float* __restrict__ w, float* __restrict__ part) {
  int mt = blockIdx.x & 31;
  int kc = blockIdx.x >> 5;
  int b0 = mt * 16;
  int tid = threadIdx.x;
  int lane = tid & 63; int nt = tid >> 6;
  int lm = lane & 15, lq = lane >> 4;
  int s0 = kc*36 + (kc < 8 ? kc : 8);
  int cnt = 36 + (kc < 8 ? 1 : 0);
  const float* arow = c2 + (size_t)(b0 + lm)*9344;
  const float* brow = w + (size_t)(nt*16 + lm)*9344;
  f32x4 acc = {0.f, 0.f, 0.f, 0.f};
  int koff = s0*16 + lq*4;
  #pragma unroll 4
  for (int i = 0; i < cnt; ++i, koff += 16) {
    s16x4 af = pk4(*(const float4*)(arow + koff));
    s16x4 bf = pk4(*(const float4*)(brow + koff));
    acc = mm16(af, bf, acc);
  }
  float* dst = part + (size_t)kc*32768;
  #pragma unroll
  for (int r = 0; r < 4; ++r)
    dst[(size_t)(b0 + lq*4 + r)*64 + nt*16 + lm] = acc[r];
}

// ---------------- K5: patch embed via MFMA, one block per batch
__global__ __launch_bounds__(256) void k_patch(const float* __restrict__ xs,
    const unsigned short* __restrict__ pwt, const float* __restrict__ pb,
    const float* __restrict__ cls, const float* __restrict__ pos, float* __restrict__ x) {
  int b = blockIdx.x;
  int tid = threadIdx.x;
  int lane = tid & 63; int nt = tid >> 6;
  int lm = lane & 15, lq = lane >> 4;
  __shared__ unsigned short P_s[304*36];

  const float* src = xs + (size_t)b*7500;
  for (int i = tid; i < 304*32; i += 256) {
    int row = i >> 5, k = i & 31;
    unsigned short v = 0;
    if (row >= 1 && row <= 300 && k < 25) v = f2bf(src[(row-1)*25 + k]);
    P_s[row*36 + k] = v;
  }
  __syncthreads();

  int d = nt*16 + lm;
  s16x4 Bf0 = *(const s16x4*)&pwt[d*32 + lq*4];
  s16x4 Bf1 = *(const s16x4*)&pwt[d*32 + 16 + lq*4];
  float pbd = pb[d];
  float clsd = cls[d];
  for (int rt = 0; rt < 19; ++rt) {
    const unsigned short* prow = &P_s[(rt*16 + lm)*36];
    s16x4 A0 = *(const s16x4*)&prow[lq*4];
    s16x4 A1 = *(const s16x4*)&prow[16 + lq*4];
    f32x4 acc = {0.f,0.f,0.f,0.f};
    acc = mm16(A0, Bf0, acc);
    acc = mm16(A1, Bf1, acc);
    #pragma unroll
    for (int r = 0; r < 4; ++r) {
      int t = rt*16 + lq*4 + r;
      if (t < SEQ) {
        float val = acc[r] + pbd + pos[t*64 + d];
        if (t == 0) val = clsd + pos[d];
        x[((size_t)b*SEQ + t)*64 + d] = val;
      }
    }
  }
}

// ---------------- K7: FULL TRANSFORMER LAYER, one block per batch b, 4 waves = 4 heads.
// A: LN1 -> xn_s (once). B: K/V fragments to registers (Q recomputed per pair).
// C: attention in 10 lockstep pairs; softmax denominator computed ON THE MFMA PIPE
//    (mm32(P, ones) rowsum: reg r holds l for the same query as o[r] — no shuffles);
//    ao overwrites this pair's xn_s rows. D: proj+LN2+FF from LDS ao.
__global__ __launch_bounds__(256) void k_layer(float* __restrict__ x,
    const float* __restrict__ g, const float* __restrict__ bt,
    const float* __restrict__ qkvw,
    const float* __restrict__ w, const float* __restrict__ bias,
    const float* __restrict__ g2, const float* __restrict__ bt2,
    const float* __restrict__ w1, const float* __restrict__ b1,
    const float* __restrict__ w2, const float* __restrict__ b2) {
  int b = blockIdx.x;
  int tid = threadIdx.x;
  int lane = tid & 63, h = tid >> 6;    // wave = head
  int lm = lane & 15, lq = lane >> 4;
  __shared__ unsigned short xn_s[304*68];  // 41,344 B; rows become ao after their pair

  const short ONE = (short)0x3F80;     // bf16 1.0
  const s16x8 ones8 = {ONE,ONE,ONE,ONE,ONE,ONE,ONE,ONE};
  const s16x4 ones4 = {ONE,ONE,ONE,ONE};

  // ---- phase A: LN1 rows -> xn_s bf16 (once per b)
  for (int rr = tid; rr < 304; rr += 256) {
    int src = rr < 301 ? rr : 300;
    const float4* xp = (const float4*)(x + ((size_t)b*SEQ + src)*64);
    float4 xv[16];
    #pragma unroll
    for (int i = 0; i < 16; ++i) xv[i] = xp[i];
    float m = 0.f;
    #pragma unroll
    for (int i = 0; i < 16; ++i) m += xv[i].x + xv[i].y + xv[i].z + xv[i].w;
    m *= (1.f/64.f);
    float var = 0.f;
    #pragma unroll
    for (int i = 0; i < 16; ++i) {
      float a = xv[i].x-m, bb = xv[i].y-m, c = xv[i].z-m, dd = xv[i].w-m;
      var += a*a + bb*bb + c*c + dd*dd;
    }
    float rs = rsqrtf(var*(1.f/64.f) + 1e-5f);
    const float4* g4 = (const float4*)g;
    const float4* b4 = (const float4*)bt;
    #pragma unroll
    for (int i = 0; i < 16; ++i) {
      float4 gg = g4[i]; float4 bb = b4[i];
      float e0 = (xv[i].x-m)*rs*gg.x + bb.x;
      float e1 = (xv[i].y-m)*rs*gg.y + bb.y;
      float e2 = (xv[i].z-m)*rs*gg.z + bb.z;
      float e3 = (xv[i].w-m)*rs*gg.w + bb.w;
      *(uint2*)&xn_s[rr*68 + i*4] = make_uint2(pkbf(e0, e1), pkbf(e2, e3));
    }
  }

  // ---- per-head weight fragments
  s16x4 WqA[4], WkA[4], WvB[4];
  #pragma unroll
  for (int c = 0; c < 4; ++c) {
    float4 wq = *(const float4*)(qkvw + (size_t)(h*16 + lm)*64 + c*16 + lq*4);
    WqA[c] = pk4f(wq.x*QSCALE, wq.y*QSCALE, wq.z*QSCALE, wq.w*QSCALE);
    WkA[c] = pk4(*(const float4*)(qkvw + (size_t)(64 + h*16 + lm)*64 + c*16 + lq*4));
    WvB[c] = pk4(*(const float4*)(qkvw + (size_t)(128 + h*16 + lm)*64 + c*16 + lq*4));
  }
  __syncthreads();

  // ---- phase B: K (swapped: lane=token) and V^T (lane=dim) into registers
  s16x4 Kreg[19], Vreg[19];
  #pragma unroll
  for (int rt = 0; rt < 19; ++rt) {
    s16x4 Af[4];
    #pragma unroll
    for (int c = 0; c < 4; ++c)
      Af[c] = *(const s16x4*)&xn_s[(rt*16 + lm)*68 + c*16 + lq*4];
    f32x4 aK = {0.f,0.f,0.f,0.f}, aV = {0.f,0.f,0.f,0.f};
    #pragma unroll
    for (int c = 0; c < 4; ++c) {
      aK = mm16(WkA[c], Af[c], aK);
      aV = mm16(Af[c], WvB[c], aV);
    }
    Kreg[rt] = pk4f(aK[0], aK[1], aK[2], aK[3]);
    Vreg[rt] = pk4f(aV[0], aV[1], aV[2], aV[3]);
  }

  // ---- phase C: attention, 10 lockstep pairs; ao overwrites xn_s rows of the pair
  for (int pi = 0; pi < 10; ++pi) {
    int qt0 = 2*pi;
    int qt1 = 2*pi + 1;
    bool two = (qt1 < 19);
    int qt1c = two ? qt1 : qt0;
    // read this pair's Q rows from xn_s (all heads), project to fragments
    s16x4 qb0, qb1;
    {
      s16x4 Af0[4], Af1[4];
      #pragma unroll
      for (int c = 0; c < 4; ++c) {
        Af0[c] = *(const s16x4*)&xn_s[(qt0*16 + lm)*68 + c*16 + lq*4];
        Af1[c] = *(const s16x4*)&xn_s[(qt1c*16 + lm)*68 + c*16 + lq*4];
      }
      f32x4 a0 = {0.f,0.f,0.f,0.f}, a1 = {0.f,0.f,0.f,0.f};
      #pragma unroll
      for (int c = 0; c < 4; ++c) {
        a0 = mm16(WqA[c], Af0[c], a0);
        a1 = mm16(WqA[c], Af1[c], a1);
      }
      qb0 = pk4f(a0[0], a0[1], a0[2], a0[3]);
      qb1 = pk4f(a1[0], a1[1], a1[2], a1[3]);
    }
    __syncthreads();   // all heads done reading pair-pi rows; writes may begin
    f32x4 o0 = {0.f,0.f,0.f,0.f}, o1 = {0.f,0.f,0.f,0.f};
    f32x4 la0 = {0.f,0.f,0.f,0.f}, la1 = {0.f,0.f,0.f,0.f};
    #pragma unroll
    for (int t = 0; t < 9; ++t) {
      s16x4 kaa = Kreg[2*t];
      s16x4 kab = Kreg[2*t + 1];
      s16x8 vb = cat8(Vreg[2*t], Vreg[2*t + 1]);
      f32x4 z = {0.f,0.f,0.f,0.f};
      f32x4 s0a = mm16(kaa, qb0, z);
      f32x4 s0b = mm16(kab, qb0, z);
      f32x4 s1a = mm16(kaa, qb1, z);
      f32x4 s1b = mm16(kab, qb1, z);
      float p00 = EX2(s0a[0]), p01 = EX2(s0a[1]), p02 = EX2(s0a[2]), p03 = EX2(s0a[3]);
      float p04 = EX2(s0b[0]), p05 = EX2(s0b[1]), p06 = EX2(s0b[2]), p07 = EX2(s0b[3]);
      float p10 = EX2(s1a[0]), p11 = EX2(s1a[1]), p12 = EX2(s1a[2]), p13 = EX2(s1a[3]);
      float p14 = EX2(s1b[0]), p15 = EX2(s1b[1]), p16 = EX2(s1b[2]), p17 = EX2(s1b[3]);
      s16x8 pa0 = cat8(pk4f(p00, p01, p02, p03), pk4f(p04, p05, p06, p07));
      s16x8 pa1 = cat8(pk4f(p10, p11, p12, p13), pk4f(p14, p15, p16, p17));
      o0  = mm32(pa0, vb, o0);
      la0 = mm32(pa0, ones8, la0);
      o1  = mm32(pa1, vb, o1);
      la1 = mm32(pa1, ones8, la1);
    }
    { // tail tile kt=18: keys 288..303, mask >= 301
      s16x4 ka = Kreg[18];
      s16x4 vb = Vreg[18];
      f32x4 z = {0.f,0.f,0.f,0.f};
      f32x4 st0 = mm16(ka, qb0, z);
      f32x4 st1 = mm16(ka, qb1, z);
      int kbase = 288 + lq*4;
      float p00 = (kbase + 0 < SEQ) ? EX2(st0[0]) : 0.f;
      float p01 = (kbase + 1 < SEQ) ? EX2(st0[1]) : 0.f;
      float p02 = (kbase + 2 < SEQ) ? EX2(st0[2]) : 0.f;
      float p03 = (kbase + 3 < SEQ) ? EX2(st0[3]) : 0.f;
      float p10 = (kbase + 0 < SEQ) ? EX2(st1[0]) : 0.f;
      float p11 = (kbase + 1 < SEQ) ? EX2(st1[1]) : 0.f;
      float p12 = (kbase + 2 < SEQ) ? EX2(st1[2]) : 0.f;
      float p13 = (kbase + 3 < SEQ) ? EX2(st1[3]) : 0.f;
      s16x4 pa0 = pk4f(p00, p01, p02, p03);
      s16x4 pa1 = pk4f(p10, p11, p12, p13);
      o0  = mm16(pa0, vb, o0);
      la0 = mm16(pa0, ones4, la0);
      o1  = mm16(pa1, vb, o1);
      la1 = mm16(pa1, ones4, la1);
    }
    // la[r] = softmax denominator for the SAME query as o[r] — direct normalize
    #pragma unroll
    for (int r = 0; r < 4; ++r) {
      int q0 = qt0*16 + lq*4 + r;
      if (q0 < SEQ) xn_s[q0*68 + h*16 + lm] = f2bf(o0[r] / la0[r]);
      if (two) {
        int q1 = qt1*16 + lq*4 + r;
        if (q1 < SEQ) xn_s[q1*68 + h*16 + lm] = f2bf(o1[r] / la1[r]);
      }
    }
  }
  __syncthreads();   // ao (in LDS, xn_s) complete for batch b
#if __has_builtin(__builtin_amdgcn_sched_barrier)
  __builtin_amdgcn_sched_barrier(0);   // keep phase-D loads out of phase C
#endif

  // ---- phase D: attn-out proj + residual + LN2 + FF + residual (ao from LDS)
  {
    s16x4 Bf[4][4];
    #pragma unroll
    for (int nt = 0; nt < 4; ++nt) {
      #pragma unroll
      for (int c = 0; c < 4; ++c) {
        float4 wf = *(const float4*)(w + (size_t)(nt*16 + lm)*64 + c*16 + lq*4);
        Bf[nt][c] = pk4(wf);
      }
    }
    float biasv[4], gv[4], btv[4], b2v[4];
    float w1r[8][4], w2r[4][8];
    float b1v[8];
    #pragma unroll
    for (int nt = 0; nt < 4; ++nt) {
      biasv[nt] = bias[nt*16 + lm];
      gv[nt]    = g2[nt*16 + lm];
      btv[nt]   = bt2[nt*16 + lm];
      b2v[nt]   = b2[nt*16 + lm];
      #pragma unroll
      for (int t = 0; t < 8; ++t) w2r[nt][t] = w2[(nt*16 + lm)*8 + t];
    }
    #pragma unroll
    for (int t = 0; t < 8; ++t) {
      b1v[t] = b1[t];
      #pragma unroll
      for (int nt = 0; nt < 4; ++nt) w1r[t][nt] = w1[t*64 + nt*16 + lm];
    }

    for (int rt = h; rt < 19; rt += 4) {
      int rsrc = rt*16 + lm; if (rsrc > 300) rsrc = 300;
      const unsigned short* arow = &xn_s[rsrc*68];
      int row0 = rt*16 + lq*4;
      float xpre[4][4];
      #pragma unroll
      for (int r = 0; r < 4; ++r) {
        int row = row0 + r; int rs2 = row > 300 ? 300 : row;
        const float* xr = x + ((size_t)b*SEQ + rs2)*64;
        #pragma unroll
        for (int nt = 0; nt < 4; ++nt) xpre[r][nt] = xr[nt*16 + lm];
      }
      f32x4 acc[4];
      #pragma unroll
      for (int nt = 0; nt < 4; ++nt)
        acc[nt] = (f32x4){biasv[nt], biasv[nt], biasv[nt], biasv[nt]};
      #pragma unroll
      for (int c = 0; c < 4; ++c) {
        s16x4 af = *(const s16x4*)(arow + c*16 + lq*4);
        #pragma unroll
        for (int nt = 0; nt < 4; ++nt) acc[nt] = mm16(af, Bf[nt][c], acc[nt]);
      }
      float v[4][4];
      #pragma unroll
      for (int r = 0; r < 4; ++r)
        #pragma unroll
        for (int nt = 0; nt < 4; ++nt) v[r][nt] = acc[nt][r] + xpre[r][nt];
      #pragma unroll
      for (int r = 0; r < 4; ++r) {
        float s = (v[r][0] + v[r][1]) + (v[r][2] + v[r][3]);
        s += __shfl_xor(s, 1, 64); s += __shfl_xor(s, 2, 64);
        s += __shfl_xor(s, 4, 64); s += __shfl_xor(s, 8, 64);
        float m = s * (1.f/64.f);
        float c0 = v[r][0]-m, c1 = v[r][1]-m, c2 = v[r][2]-m, c3 = v[r][3]-m;
        float s2 = (c0*c0 + c1*c1) + (c2*c2 + c3*c3);
        s2 += __shfl_xor(s2, 1, 64); s2 += __shfl_xor(s2, 2, 64);
        s2 += __shfl_xor(s2, 4, 64); s2 += __shfl_xor(s2, 8, 64);
        float rs = rsqrtf(s2*(1.f/64.f) + 1e-5f);
        float xn0 = c0*rs*gv[0] + btv[0];
        float xn1 = c1*rs*gv[1] + btv[1];
        float xn2 = c2*rs*gv[2] + btv[2];
        float xn3 = c3*rs*gv[3] + btv[3];
        float hg[8];
        #pragma unroll
        for (int t = 0; t < 8; ++t) {
          float p = xn0*w1r[t][0] + xn1*w1r[t][1] + xn2*w1r[t][2] + xn3*w1r[t][3];
          p += __shfl_xor(p, 1, 64); p += __shfl_xor(p, 2, 64);
          p += __shfl_xor(p, 4, 64); p += __shfl_xor(p, 8, 64);
          hg[t] = gelu_f(p + b1v[t]);
        }
        int row = row0 + r;
        if (row < SEQ) {
          float* xw = x + ((size_t)b*SEQ + row)*64;
          #pragma unroll
          for (int nt = 0; nt < 4; ++nt) {
            float o = 0.f;
            #pragma unroll
            for (int t = 0; t < 8; ++t) o += hg[t]*w2r[nt][t];
            xw[nt*16 + lm] = v[r][nt] + o + b2v[nt];
          }
        }
      }
    }
  }
}

// ---------------- K10: head (sums dense1 split-K partials + bias inline)
__global__ __launch_bounds__(128) void k_head(const float* __restrict__ x,
    const float* __restrict__ part, const float* __restrict__ d1b,
    const float* __restrict__ g, const float* __restrict__ bt,
    const float* __restrict__ hw, const float* __restrict__ hb, float* __restrict__ out) {
  int b = blockIdx.x; int t = threadIdx.x; int lane = t & 63; int wv = t >> 6;
  float v;
  if (t < 64) {
    v = x[(size_t)b*SEQ*64 + t];
  } else {
    int o = t - 64;
    float acc = d1b[o];
    #pragma unroll
    for (int kc = 0; kc < 16; ++kc) acc += part[(size_t)kc*32768 + b*64 + o];
    v = acc;
  }
  __shared__ float rbuf[2];
  __shared__ float z_s[128];
  float s = v;
  #pragma unroll
  for (int o = 32; o; o >>= 1) s += __shfl_down(s, o, 64);
  if (lane == 0) rbuf[wv] = s;
  __syncthreads();
  float m = (rbuf[0] + rbuf[1]) * (1.f/128.f);
  __syncthreads();
  float c = v - m;
  float s2 = c*c;
  #pragma unroll
  for (int o = 32; o; o >>= 1) s2 += __shfl_down(s2, o, 64);
  if (lane == 0) rbuf[wv] = s2;
  __syncthreads();
  float var = (rbuf[0] + rbuf[1]) * (1.f/128.f);
  z_s[t] = c * rsqrtf(var + 1e-5f) * g[t] + bt[t];
  __syncthreads();
  if (t < 16) {
    float a = hb[t];
    const float* wr = hw + t*128;
    #pragma unroll 8
    for (int j = 0; j < 128; ++j) a += z_s[j]*wr[j];
    out[(size_t)b*16 + t] = a;
  }
}

extern "C" void kernel_launch(void* const* d_in, const int* in_sizes, int n_in,
                              void* d_out, int out_size, void* d_ws, size_t ws_size,
                              hipStream_t stream) {
  const float* input      = (const float*)d_in[0];
  const float* sse_w      = (const float*)d_in[1];
  const float* sse_b      = (const float*)d_in[2];
  const float* conv1_w    = (const float*)d_in[3];
  const float* conv1_b    = (const float*)d_in[4];
  const float* conv2_w    = (const float*)d_in[5];
  const float* conv2_b    = (const float*)d_in[6];
  const float* dense1_w   = (const float*)d_in[7];
  const float* dense1_b   = (const float*)d_in[8];
  const float* patch_w    = (const float*)d_in[9];
  const float* patch_b    = (const float*)d_in[10];
  const float* cls_token  = (const float*)d_in[11];
  const float* pos_emb    = (const float*)d_in[12];
  const float* ln1_g      = (const float*)d_in[13];
  const float* ln1_b      = (const float*)d_in[14];
  const float* qkv_w      = (const float*)d_in[15];
  const float* attn_out_w = (const float*)d_in[16];
  const float* attn_out_b = (const float*)d_in[17];
  const float* ln2_g      = (const float*)d_in[18];
  const float* ln2_b      = (const float*)d_in[19];
  const float* ff1_w      = (const float*)d_in[20];
  const float* ff1_b      = (const float*)d_in[21];
  const float* ff2_w      = (const float*)d_in[22];
  const float* ff2_b      = (const float*)d_in[23];
  const float* head_ln_g  = (const float*)d_in[24];
  const float* head_ln_b  = (const float*)d_in[25];
  const float* head_w     = (const float*)d_in[26];
  const float* head_b     = (const float*)d_in[27];
  float* out = (float*)d_out;

  float* ws = (float*)d_ws;
  float* xs  = ws;                    // 3,840,000 (dead after k_patch -> reused for part)
  float* part = ws;                   // 16*32768 floats (dense1 partials, after k_patch)
  float* y   = xs + 3840000;          // 32,768 floats region for prep outputs
  unsigned short* wt2g = (unsigned short*)y;            // 96*148 u16
  unsigned short* pwt  = (unsigned short*)(y + 16384);  // 64*32 u16
  float* x   = y + 32768;             // 9,863,168
  float* R   = x + 9863168;           // shared region
  float* c2  = R + 21676032;          // conv phase

  k_prep  <<<56, 256, 0, stream>>>(conv2_w, wt2g);
  k_prep2 <<<8, 256, 0, stream>>>(patch_w, pwt);
  k_sse   <<<NB*25, 64, 0, stream>>>(input, sse_w, sse_b, xs);
  k_conv12<<<NB*4, 256, 0, stream>>>(xs, conv1_w, conv1_b, wt2g, conv2_b, c2);
  k_patch <<<NB, 256, 0, stream>>>(xs, pwt, patch_b, cls_token, pos_emb, x);
  k_dense1<<<512, 256, 0, stream>>>(c2, dense1_w, part);
  for (int i = 0; i < 5; ++i) {
    k_layer<<<NB, 256, 0, stream>>>(x, ln1_g + i*64, ln1_b + i*64,
                 qkv_w + (size_t)i*192*64,
                 attn_out_w + (size_t)i*4096, attn_out_b + i*64,
                 ln2_g + i*64, ln2_b + i*64,
                 ff1_w + (size_t)i*512, ff1_b + i*8, ff2_w + (size_t)i*512, ff2_b + i*64);
  }
  k_head<<<NB, 128, 0, stream>>>(x, part, dense1_b, head_ln_g, head_ln_b, head_w, head_b, out);
}